// Round 1
// 211.095 us; speedup vs baseline: 1.0512x; 1.0512x over previous
//
#include <hip/hip_runtime.h>
#include <hip/hip_bf16.h>

// Problem constants (from reference setup_inputs)
#define BB    4
#define NTOT  16384
#define CC    256
#define HH    8
#define DD    64
#define HD    512
#define OUTC  256

typedef unsigned short u16;
typedef unsigned int u32;
typedef __attribute__((ext_vector_type(8))) short bf16x8;   // 8 bf16 in 4 VGPRs
typedef __attribute__((ext_vector_type(4))) float f32x4;
typedef __attribute__((ext_vector_type(4))) short u16x4;
typedef __attribute__((ext_vector_type(4))) u32 u32x4;

__device__ __forceinline__ float b2f(u16 u) {
    union { float f; u32 i; } x; x.i = ((u32)u) << 16; return x.f;
}
__device__ __forceinline__ u16 f2b(float f) {
    union { float f; u32 i; } x; x.f = f;
    u32 r = x.i + 0x7fffu + ((x.i >> 16) & 1u);   // round-to-nearest-even
    return (u16)(r >> 16);
}

#define GLD(gp, lp) __builtin_amdgcn_global_load_lds( \
    (const __attribute__((address_space(1))) void*)(gp), \
    (__attribute__((address_space(3))) void*)(lp), 16, 0, 0)

#define MFMA(a, b, c) __builtin_amdgcn_mfma_f32_16x16x32_bf16((a), (b), (c), 0, 0, 0)

// ---------------------------------------------------------------------------
// wcvt: 4 weight matrices (each 131072 f32) -> bf16. grid (64, 1, 4).
// ---------------------------------------------------------------------------
__global__ __launch_bounds__(256) void wcvt(
    const float* __restrict__ Wq, const float* __restrict__ Wk,
    const float* __restrict__ Wv, const float* __restrict__ Wo,
    u16* __restrict__ q, u16* __restrict__ k,
    u16* __restrict__ v, u16* __restrict__ o)
{
    const int z = blockIdx.z;
    const float* src = z == 0 ? Wq : z == 1 ? Wk : z == 2 ? Wv : Wo;
    u16* dst = z == 0 ? q : z == 1 ? k : z == 2 ? v : o;
    const int i = (blockIdx.x * 256 + threadIdx.x) * 8;
    const float4 a = *(const float4*)(src + i);
    const float4 b = *(const float4*)(src + i + 4);
    union { bf16x8 v; u16 s[8]; } w;
    w.s[0] = f2b(a.x); w.s[1] = f2b(a.y); w.s[2] = f2b(a.z); w.s[3] = f2b(a.w);
    w.s[4] = f2b(b.x); w.s[5] = f2b(b.y); w.s[6] = f2b(b.z); w.s[7] = f2b(b.w);
    *(bf16x8*)(dst + i) = w.v;
}

// ---------------------------------------------------------------------------
// ggemm v3: Gp[z][i][j] = sum_{n in chunk ck} bf16(u[b][n][i])*bf16(u[b][n][j])
// (unchanged proven kernel). grid (256), 512 thr.
// ---------------------------------------------------------------------------
__global__ __launch_bounds__(512) void ggemm(
    const float* __restrict__ u, float* __restrict__ Gp, float* __restrict__ suP)
{
    __shared__ u32 Ts[16 * 290];   // 18.6 KB
    const int z = blockIdx.x, b = z >> 6, ck = z & 63;
    const float* base = u + (long long)b * NTOT * CC + (long long)ck * 256 * CC;
    const int t = threadIdx.x, w = t >> 6, l = t & 63;
    const int wy = w >> 1, wx = w & 1;
    const int r16 = l & 15, quad = l >> 4;
    const int sp = t >> 5;          // n-pair 0..15
    const int sq = t & 31;          // c-octet 0..31

    const int csa0 = 9 * ((wy * 64 + r16) >> 3) + (r16 & 7);     // + 18*i
    const int csb0 = 9 * ((wx * 128 + r16) >> 3) + (r16 & 7);    // + 18*j
    const int pr0 = 4 * quad * 290;

    f32x4 acc[4][8] = {};
    float su = 0.f;

    float4 a0, a1, b0, b1;
    {
        const float* src = base + (long long)(2 * sp) * CC + sq * 8;
        a0 = *(const float4*)src;       a1 = *(const float4*)(src + 4);
        b0 = *(const float4*)(src + CC); b1 = *(const float4*)(src + CC + 4);
    }

    for (int it = 0; it < 8; it++) {
        __syncthreads();   // prev iter's LDS reads complete (no-op first iter)
        {   // cvt + pair-pack + scatter-write (conflict-free via 9-stride)
            u32 pk[8];
            pk[0] = (u32)(u16)f2b(a0.x) | ((u32)f2b(b0.x) << 16);
            pk[1] = (u32)(u16)f2b(a0.y) | ((u32)f2b(b0.y) << 16);
            pk[2] = (u32)(u16)f2b(a0.z) | ((u32)f2b(b0.z) << 16);
            pk[3] = (u32)(u16)f2b(a0.w) | ((u32)f2b(b0.w) << 16);
            pk[4] = (u32)(u16)f2b(a1.x) | ((u32)f2b(b1.x) << 16);
            pk[5] = (u32)(u16)f2b(a1.y) | ((u32)f2b(b1.y) << 16);
            pk[6] = (u32)(u16)f2b(a1.z) | ((u32)f2b(b1.z) << 16);
            pk[7] = (u32)(u16)f2b(a1.w) | ((u32)f2b(b1.w) << 16);
            u32* dst = Ts + sp * 290 + 9 * sq;
#pragma unroll
            for (int k = 0; k < 8; k++) dst[k] = pk[k];
        }
        if (it < 7) {   // prefetch next 32-n slab (overlaps barrier+compute)
            const float* src = base + (long long)((it + 1) * 32 + 2 * sp) * CC + sq * 8;
            a0 = *(const float4*)src;       a1 = *(const float4*)(src + 4);
            b0 = *(const float4*)(src + CC); b1 = *(const float4*)(src + CC + 4);
        }
        __syncthreads();

        if (t < 256) {   // su partial for channel c = t
            const int cs = 9 * (t >> 3) + (t & 7);
            float s1 = 0.f;
#pragma unroll
            for (int p = 0; p < 16; p++) {
                u32 v = Ts[p * 290 + cs];
                s1 += b2f((u16)(v & 0xffff)) + b2f((u16)(v >> 16));
            }
            su += s1;
        }

        bf16x8 a[4], bb[8];
#pragma unroll
        for (int i = 0; i < 4; i++) {
            const int cs = csa0 + 18 * i;
            union { u32x4 u4; bf16x8 h; } f;
            f.u4[0] = Ts[pr0 + cs];       f.u4[1] = Ts[pr0 + 290 + cs];
            f.u4[2] = Ts[pr0 + 580 + cs]; f.u4[3] = Ts[pr0 + 870 + cs];
            a[i] = f.h;
        }
#pragma unroll
        for (int j = 0; j < 8; j++) {
            const int cs = csb0 + 18 * j;
            union { u32x4 u4; bf16x8 h; } f;
            f.u4[0] = Ts[pr0 + cs];       f.u4[1] = Ts[pr0 + 290 + cs];
            f.u4[2] = Ts[pr0 + 580 + cs]; f.u4[3] = Ts[pr0 + 870 + cs];
            bb[j] = f.h;
        }
#pragma unroll
        for (int i = 0; i < 4; i++)
#pragma unroll
            for (int j = 0; j < 8; j++)
                acc[i][j] = MFMA(a[i], bb[j], acc[i][j]);
    }

    float* Cp = Gp + (long long)z * 65536;
#pragma unroll
    for (int i = 0; i < 4; i++)
#pragma unroll
        for (int j = 0; j < 8; j++)
#pragma unroll
            for (int rr = 0; rr < 4; rr++)
                Cp[(wy * 64 + 16 * i + quad * 4 + rr) * 256 + wx * 128 + 16 * j + r16]
                    = acc[i][j][rr];
    if (t < 256) suP[z * 256 + t] = su;
}

// ---------------------------------------------------------------------------
// gred: Gb[b][i][j] = bf16(sum_{ck<64} Gp), f32x4 per thread (4 cols).
// grid (64, 4), 256 thr; block x==0 also reduces suP -> su.
// ---------------------------------------------------------------------------
__global__ __launch_bounds__(256) void gred(
    const float* __restrict__ Gp, const float* __restrict__ suP,
    u16* __restrict__ Gb, float* __restrict__ su)
{
    const int b = blockIdx.y, t = threadIdx.x;
    const int row = blockIdx.x * 4 + (t >> 6);
    const int col = (t & 63) * 4;
    const float* p = Gp + (long long)(b * 64) * 65536 + row * 256 + col;
    f32x4 s = {};
#pragma unroll
    for (int ck = 0; ck < 64; ck++) {
        f32x4 v = *(const f32x4*)(p + (long long)ck * 65536);
        s[0] += v[0]; s[1] += v[1]; s[2] += v[2]; s[3] += v[3];
    }
    union { u16x4 v; u16 q[4]; } pk;
#pragma unroll
    for (int k = 0; k < 4; k++) pk.q[k] = f2b(s[k]);
    *(u16x4*)(Gb + (long long)b * 65536 + row * 256 + col) = pk.v;

    if (blockIdx.x == 0) {
        float s2 = 0.f;
#pragma unroll
        for (int ck = 0; ck < 64; ck++) s2 += suP[(b * 64 + ck) * 256 + t];
        su[b * 256 + t] = s2;
    }
}

// ---------------------------------------------------------------------------
// skvz: replaces the serial back half of the old midend, per (b,h).
// Inputs: P2[b][1024][256] = [Wk;Wv]_stacked x G (bf16, from gemm_bt), su.
// stats: e2[a] = dot(P2 row, W row) (direct, no atomics / no Pv MFMA);
// S = Pk Wv^T with fragments read straight from global (row-major,
// k-contiguous); kv -> kvT LDS; WqT LDS staging + Y-phase (proven code).
// grid (32), 256 thr.
// ---------------------------------------------------------------------------
__global__ __launch_bounds__(256) void skvz(
    const u16* __restrict__ P2, const float* __restrict__ su,
    const u16* __restrict__ Wk_b, const u16* __restrict__ Wv_b,
    const u16* __restrict__ Wq_b, u16* __restrict__ Zt)
{
    __shared__ u16 pool[20480];   // kvTL 8KB + WqTL 32KB
    __shared__ float mkL[64], rkL[64], mvL[64], rvL[64];

    const int bx = blockIdx.x, b = bx >> 3, h = bx & 7;
    const int t = threadIdx.x, w = t >> 6, l = t & 63;
    const int r16 = l & 15, quad = l >> 4;

    const u16* WkH = Wk_b + (h * 64) * 256;
    const u16* WvH = Wv_b + (h * 64) * 256;
    const u16* PkH = P2 + (long long)b * 262144 + (h * 64) * 256;
    const u16* PvH = P2 + (long long)b * 262144 + (512 + h * 64) * 256;

    // ---- stats: 2 threads per row (128 rows: 64 k + 64 v) ----
    {
        const int row = t >> 1, half = t & 1;
        const u16* Prow = (row < 64 ? PkH + row * 256 : PvH + (row - 64) * 256) + half * 128;
        const u16* Wrow = (row < 64 ? WkH + row * 256 : WvH + (row - 64) * 256) + half * 128;
        const float* suB = su + b * 256 + half * 128;
        float e2 = 0.f, m = 0.f;
#pragma unroll
        for (int c8 = 0; c8 < 16; c8++) {
            bf16x8 pw = *(const bf16x8*)(Prow + c8 * 8);
            bf16x8 ww = *(const bf16x8*)(Wrow + c8 * 8);
#pragma unroll
            for (int k = 0; k < 8; k++) {
                const float wv_ = b2f((u16)ww[k]);
                e2 += b2f((u16)pw[k]) * wv_;
                m  += wv_ * suB[c8 * 8 + k];
            }
        }
        e2 += __shfl_xor(e2, 1);
        m  += __shfl_xor(m, 1);
        if (half == 0) {
            m *= (1.0f / NTOT);
            const float r = rsqrtf(e2 * (1.0f / NTOT) - m * m + 1e-5f);
            if (row < 64) { mkL[row] = m; rkL[row] = r; }
            else          { mvL[row - 64] = m; rvL[row - 64] = r; }
        }
    }
    __syncthreads();

    // ---- S-phase: S[d,e] = sum_c Pk[d,c] Wv[e,c]; frags from global ----
    const int mh = (w >> 1) * 32, nh = (w & 1) * 32;
    float mkR[2][4], rkR[2][4], mvR[2], rvR[2];
#pragma unroll
    for (int i = 0; i < 2; i++)
#pragma unroll
        for (int rr = 0; rr < 4; rr++) {
            mkR[i][rr] = mkL[mh + 16 * i + quad * 4 + rr];
            rkR[i][rr] = rkL[mh + 16 * i + quad * 4 + rr];
        }
#pragma unroll
    for (int j = 0; j < 2; j++) {
        mvR[j] = mvL[nh + 16 * j + r16];
        rvR[j] = rvL[nh + 16 * j + r16];
    }

    f32x4 accs[2][2] = {};
    for (int ch = 0; ch < 8; ch++) {
        const int ko = quad * 8;
        bf16x8 ap[2], bv[2];
#pragma unroll
        for (int i = 0; i < 2; i++)
            ap[i] = *(const bf16x8*)(PkH + (mh + 16 * i + r16) * 256 + ch * 32 + ko);
#pragma unroll
        for (int j = 0; j < 2; j++)
            bv[j] = *(const bf16x8*)(WvH + (nh + 16 * j + r16) * 256 + ch * 32 + ko);
#pragma unroll
        for (int i = 0; i < 2; i++)
#pragma unroll
            for (int j = 0; j < 2; j++)
                accs[i][j] = MFMA(ap[i], bv[j], accs[i][j]);
    }

    // ---- kv -> kvTL; WqTL ----
    u16* kvTL = pool;            // 8 KB
    u16* WqTL = pool + 4096;     // 32 KB
#pragma unroll
    for (int i = 0; i < 2; i++)
#pragma unroll
        for (int j = 0; j < 2; j++)
#pragma unroll
            for (int rr = 0; rr < 4; rr++) {
                const int d = mh + 16 * i + quad * 4 + rr;
                const int e = nh + 16 * j + r16;
                const float kv = rkR[i][rr] * rvR[j] *
                    (accs[i][j][rr] * (1.0f / NTOT) - mkR[i][rr] * mvR[j]);
                kvTL[(d >> 5) * 2048 + e * 32 + (d & 31)] = f2b(kv);
            }
    {
        const int d = t >> 2, q = t & 3;
        const u16* Wrow = Wq_b + (h * 64 + d) * 256 + q * 64;
#pragma unroll
        for (int s = 0; s < 8; s++) {
            bf16x8 raw = *(const bf16x8*)(Wrow + s * 8);
#pragma unroll
            for (int k = 0; k < 8; k++) {
                const int c = q * 64 + s * 8 + k;
                WqTL[(d >> 5) * 8192 + c * 32 + (d & 31)] = (u16)raw[k];
            }
        }
    }
    __syncthreads();

    // ---- Y-phase ----
    f32x4 accy[4][4] = {};
#pragma unroll
    for (int ch = 0; ch < 2; ch++) {
        const int ko = quad * 8;
        bf16x8 akv[4], bq[4];
#pragma unroll
        for (int i = 0; i < 4; i++)
            akv[i] = *(const bf16x8*)(kvTL + ch * 2048 + (16 * i + r16) * 32 + ko);
#pragma unroll
        for (int j = 0; j < 4; j++)
            bq[j] = *(const bf16x8*)(WqTL + ch * 8192 + (w * 64 + 16 * j + r16) * 32 + ko);
#pragma unroll
        for (int i = 0; i < 4; i++)
#pragma unroll
            for (int j = 0; j < 4; j++)
                accy[i][j] = MFMA(akv[i], bq[j], accy[i][j]);
    }
#pragma unroll
    for (int i = 0; i < 4; i++)
#pragma unroll
        for (int j = 0; j < 4; j++) {
            const int c = w * 64 + 16 * j + r16;
            const int e0 = 16 * i + quad * 4;
            union { u16x4 v; u16 s[4]; } pk;
#pragma unroll
            for (int rr = 0; rr < 4; rr++) pk.s[rr] = f2b(accy[i][j][rr]);
            *(u16x4*)(Zt + ((long long)(b * 256 + c)) * 512 + h * 64 + e0) = pk.v;
        }
}

// ---------------------------------------------------------------------------
// gemm_bt (proven): C[m,n] = sum_k A[m,k]*Bm[n,k] (+bias[n]); bf16 A,B.
// ---------------------------------------------------------------------------
template <typename CT>
__global__ __launch_bounds__(256) void gemm_bt(
    const u16* __restrict__ A, const u16* __restrict__ Bm,
    CT* __restrict__ C, const float* __restrict__ bias,
    int K, int lda, int ldc,
    long long aStride, long long bStride, long long cStride)
{
    __shared__ u16 As[128 * 32];
    __shared__ u16 Bs[128 * 32];

    const int bz = blockIdx.z;
    A  += (long long)bz * aStride;
    Bm += (long long)bz * bStride;
    C  += (long long)bz * cStride;

    const int m0 = blockIdx.x * 128;
    const int n0 = blockIdx.y * 128;
    const int t  = threadIdx.x;
    const int wv = t >> 6, l = t & 63;
    const int wy = wv >> 1, wx = wv & 1;
    const int r16  = l & 15;
    const int quad = l >> 4;
    const int srow = wv * 16 + (l >> 2);
    const int scol = (l & 3) * 8;

    f32x4 acc[4][4] = {};

    for (int kk = 0; kk < K; kk += 32) {
#pragma unroll
        for (int s = 0; s < 2; s++) {
            GLD(A + (long long)(m0 + s * 64 + srow) * lda + kk + scol,
                As + s * 2048 + wv * 512);
            GLD(Bm + (long long)(n0 + s * 64 + srow) * K + kk + scol,
                Bs + s * 2048 + wv * 512);
        }
        __syncthreads();

        bf16x8 a[4], b[4];
#pragma unroll
        for (int i = 0; i < 4; i++)
            a[i] = *(const bf16x8*)(As + (wy * 64 + 16 * i + r16) * 32 + quad * 8);
#pragma unroll
        for (int j = 0; j < 4; j++)
            b[j] = *(const bf16x8*)(Bs + (wx * 64 + 16 * j + r16) * 32 + quad * 8);
#pragma unroll
        for (int i = 0; i < 4; i++)
#pragma unroll
            for (int j = 0; j < 4; j++)
                acc[i][j] = MFMA(a[i], b[j], acc[i][j]);
        __syncthreads();
    }

#pragma unroll
    for (int j = 0; j < 4; j++) {
        const int col = n0 + wx * 64 + 16 * j + r16;
        const float bv = bias ? bias[col] : 0.0f;
#pragma unroll
        for (int i = 0; i < 4; i++) {
#pragma unroll
            for (int r = 0; r < 4; r++) {
                const int row = m0 + wy * 64 + 16 * i + quad * 4 + r;
                const float v = acc[i][j][r] + bv;
                if constexpr (sizeof(CT) == 2) C[(long long)row * ldc + col] = f2b(v);
                else                           C[(long long)row * ldc + col] = v;
            }
        }
    }
}

// ---------------------------------------------------------------------------
// gemm_uf32w: out[n,o] = sum_c bf16(u[b][n][c]) * Ft[b][o][c] + bo[o], f32 out.
// 128x256 tile (full 256 out-cols per block -> u f32 read ONCE), K=256,
// grid (128, 1, 4). A staged from f32 u with inline cvt; B via GLD.
// ---------------------------------------------------------------------------
__global__ __launch_bounds__(256) void gemm_uf32w(
    const float* __restrict__ uf, const u16* __restrict__ Ft,
    float* __restrict__ C, const float* __restrict__ bias)
{
    __shared__ u16 As[128 * 32];   // 8 KB
    __shared__ u16 Bs[256 * 32];   // 16 KB

    const int b = blockIdx.z;
    uf += (long long)b * NTOT * CC;
    const u16* Bm = Ft + (long long)b * 65536;
    C += (long long)b * NTOT * OUTC;

    const int m0 = blockIdx.x * 128;
    const int t  = threadIdx.x;
    const int wv = t >> 6, l = t & 63;
    const int wy = wv >> 1, wx = wv & 1;
    const int r16  = l & 15;
    const int quad = l >> 4;
    const int srow = wv * 16 + (l >> 2);
    const int scol = (l & 3) * 8;
    const int ar = t >> 1, ah = t & 1;   // A-staging: row 0..127, 16-col half

    f32x4 acc[4][8] = {};

    for (int kk = 0; kk < 256; kk += 32) {
        {   // A: load f32, cvt, 2x b128 LDS writes
            const float* s = uf + (long long)(m0 + ar) * CC + kk + ah * 16;
            float4 v0 = *(const float4*)s;
            float4 v1 = *(const float4*)(s + 4);
            float4 v2 = *(const float4*)(s + 8);
            float4 v3 = *(const float4*)(s + 12);
            union { bf16x8 v; u16 q[8]; } p0, p1;
            p0.q[0]=f2b(v0.x); p0.q[1]=f2b(v0.y); p0.q[2]=f2b(v0.z); p0.q[3]=f2b(v0.w);
            p0.q[4]=f2b(v1.x); p0.q[5]=f2b(v1.y); p0.q[6]=f2b(v1.z); p0.q[7]=f2b(v1.w);
            p1.q[0]=f2b(v2.x); p1.q[1]=f2b(v2.y); p1.q[2]=f2b(v2.z); p1.q[3]=f2b(v2.w);
            p1.q[4]=f2b(v3.x); p1.q[5]=f2b(v3.y); p1.q[6]=f2b(v3.z); p1.q[7]=f2b(v3.w);
            u16* d = As + ar * 32 + ah * 16;
            *(bf16x8*)d = p0.v;
            *(bf16x8*)(d + 8) = p1.v;
        }
#pragma unroll
        for (int s = 0; s < 4; s++)
            GLD(Bm + (long long)(s * 64 + srow) * 256 + kk + scol,
                Bs + s * 2048 + wv * 512);
        __syncthreads();

        bf16x8 a[4], bb[8];
#pragma unroll
        for (int i = 0; i < 4; i++)
            a[i] = *(const bf16x8*)(As + (wy * 64 + 16 * i + r16) * 32 + quad * 8);
#pragma unroll
        for (int j = 0; j < 8; j++)
            bb[j] = *(const bf16x8*)(Bs + (wx * 128 + 16 * j + r16) * 32 + quad * 8);
#pragma unroll
        for (int i = 0; i < 4; i++)
#pragma unroll
            for (int j = 0; j < 8; j++)
                acc[i][j] = MFMA(a[i], bb[j], acc[i][j]);
        __syncthreads();
    }

#pragma unroll
    for (int j = 0; j < 8; j++) {
        const int col = wx * 128 + 16 * j + r16;
        const float bv = bias[col];
#pragma unroll
        for (int i = 0; i < 4; i++) {
#pragma unroll
            for (int r = 0; r < 4; r++) {
                const int row = m0 + wy * 64 + 16 * i + quad * 4 + r;
                C[(long long)row * OUTC + col] = acc[i][j][r] + bv;
            }
        }
    }
}

// ---------------------------------------------------------------------------
extern "C" void kernel_launch(void* const* d_in, const int* in_sizes, int n_in,
                              void* d_out, int out_size, void* d_ws, size_t ws_size,
                              hipStream_t stream)
{
    const float* u_src = (const float*)d_in[0];
    // d_in[1] = pos_src (unused)
    const float* Wq = (const float*)d_in[2];
    const float* Wk = (const float*)d_in[3];
    const float* Wv = (const float*)d_in[4];
    const float* Wo = (const float*)d_in[5];
    const float* bo = (const float*)d_in[6];
    float* out = (float*)d_out;

    char* ws = (char*)d_ws;
    size_t off = 0;
    float* Gp  = (float*)(ws + off); off += 67108864;  // [256][256][256] f32 partials
    float* suP = (float*)(ws + off); off += 262144;    // [256][256] f32
    u16*  Gb   = (u16*)(ws + off);  off += 524288;     // [4][256][256] bf16
    u16*  Wq_b = (u16*)(ws + off);  off += 262144;
    u16*  Wk_b = (u16*)(ws + off);  off += 262144;     // adjacent to Wv_b -> stacked [1024][256]
    u16*  Wv_b = (u16*)(ws + off);  off += 262144;
    u16*  Wo_b = (u16*)(ws + off);  off += 262144;     // [256][512] bf16
    float* su  = (float*)(ws + off); off += 4096;      // [4][256] f32
    u16*  Zt   = (u16*)(ws + off);  off += 1048576;    // [4][256][512] bf16
    u16*  Ft   = (u16*)(ws + off);  off += 524288;     // [4][256][256] bf16
    u16*  P2   = (u16*)(ws + off);  off += 2097152;    // [4][1024][256] bf16 ([Wk;Wv] x G)

    const dim3 blk(256);

    // weights -> bf16
    wcvt<<<dim3(64, 1, 4), blk, 0, stream>>>(Wq, Wk, Wv, Wo, Wq_b, Wk_b, Wv_b, Wo_b);

    // G partials directly from f32 u (cvt+transpose in staging) + su partials
    ggemm<<<dim3(BB * 64), dim3(512), 0, stream>>>(u_src, Gp, suP);
    gred<<<dim3(64, BB), blk, 0, stream>>>(Gp, suP, Gb, su);

    // P2[b] = [Wk;Wv]_stacked (1024x256) x G_b (G symmetric -> B^T form exact)
    gemm_bt<u16><<<dim3(8, 2, BB), blk, 0, stream>>>(
        Wk_b, Gb, P2, nullptr, 256, 256, 256, 0, 65536, 262144);

    // stats/S/kv/Zt (short serial tail, no P-GEMM / no LDS atomics)
    skvz<<<dim3(BB * HH), blk, 0, stream>>>(P2, su, Wk_b, Wv_b, Wq_b, Zt);

    // Ft[b] = Wo Zt_b^T : [256x512]x[512x256]
    gemm_bt<u16><<<dim3(2, 2, BB), blk, 0, stream>>>(
        Wo_b, Zt, Ft, nullptr, 512, 512, 256, 0, 131072, 65536);

    // out = u Ft^T + bo (A from f32 u, inline cvt, full-width tile)
    gemm_uf32w<<<dim3(128, 1, BB), blk, 0, stream>>>(u_src, Ft, out, bo);
}